// Round 5
// baseline (320.819 us; speedup 1.0000x reference)
//
#include <hip/hip_runtime.h>

// DilatedConv1D: out[b,o,p] = bias[o] + sum_c x[b,c,p]*W[o,c,0] + x[b,c,p+2]*W[o,c,1]
// x: (8,128,32768) fp32, W: (128,128,2) fp32, bias: (128) fp32, out: (8,128,32769) fp32.
// bf16 MFMA GEMM. Round-5: dwordx4 staging (4x MLP per VGPR), occupancy 3 blocks/CU.

namespace {

constexpr int kB   = 8;
constexpr int kC   = 128;
constexpr int kT   = 32768;
constexpr int kP   = kT + 1;                    // 32769 output positions
constexpr int kOut = 128;
constexpr int kNP  = 128;                       // positions per block tile
constexpr int kNTiles = (kP + kNP - 1) / kNP;   // 257
constexpr int kLStride = 136;                   // shorts per pos-row (272 B, 16B-aligned)

typedef __attribute__((ext_vector_type(8))) short short8;
typedef __attribute__((ext_vector_type(4))) float f32x4;

// float -> bf16 bits, round-to-nearest-even (finite inputs)
__device__ __forceinline__ short f2bf(float f) {
    unsigned int u = __builtin_bit_cast(unsigned int, f);
    u += 0x7fffu + ((u >> 16) & 1u);
    return (short)(u >> 16);
}

// Fast path: all of [p0, p0+130) < kT. Thread = (g = tid>>5 -> 16 c's, chunk = tid&31 -> 4 pos).
// 16 dwordx4 loads hoisted into registers, then in-register transpose -> 8 b128 LDS writes.
__device__ __forceinline__ void stage_fast(const float* __restrict__ xb,
                                           short* __restrict__ xs,
                                           int tid, int p0) {
    const int g     = tid >> 5;
    const int chunk = tid & 31;
    const float* base = xb + p0 + chunk * 4;
    float4 r[16];
    #pragma unroll
    for (int i = 0; i < 16; ++i)
        r[i] = *reinterpret_cast<const float4*>(base + (size_t)(g * 16 + i) * kT);

    // halo pos 128,129: thread -> (c = tid&127, pos = 128 + (tid>>7))
    const int hc = tid & 127, hp = 128 + (tid >> 7);
    const float hv = xb[(size_t)hc * kT + p0 + hp];

    #pragma unroll
    for (int j = 0; j < 4; ++j) {
        short8 s0, s1;
        #pragma unroll
        for (int i = 0; i < 8; ++i) {
            s0[i] = f2bf(reinterpret_cast<const float*>(&r[i])[j]);
            s1[i] = f2bf(reinterpret_cast<const float*>(&r[i + 8])[j]);
        }
        short* row = xs + (chunk * 4 + j) * kLStride + g * 16;
        *reinterpret_cast<short8*>(row)     = s0;
        *reinterpret_cast<short8*>(row + 8) = s1;
    }
    xs[hp * kLStride + hc] = f2bf(hv);
}

// Guarded path (last 2 tiles per batch): scalar loads, per-element bound check.
__device__ __forceinline__ void stage_guard(const float* __restrict__ xb,
                                            short* __restrict__ xs,
                                            int tid, int p0) {
    const int g     = tid >> 5;
    const int chunk = tid & 31;
    #pragma unroll
    for (int j = 0; j < 4; ++j) {
        const int gp = p0 + chunk * 4 + j;
        const bool ok = gp < kT;
        short8 s0, s1;
        #pragma unroll
        for (int i = 0; i < 8; ++i) {
            const int c0 = g * 16 + i;
            s0[i] = ok ? f2bf(xb[(size_t)c0 * kT + gp]) : (short)0;
            s1[i] = ok ? f2bf(xb[(size_t)(c0 + 8) * kT + gp]) : (short)0;
        }
        short* row = xs + (chunk * 4 + j) * kLStride + g * 16;
        *reinterpret_cast<short8*>(row)     = s0;
        *reinterpret_cast<short8*>(row + 8) = s1;
    }
    const int hc = tid & 127, hp = 128 + (tid >> 7);
    const int gp = p0 + hp;
    xs[hp * kLStride + hc] = (gp < kT) ? f2bf(xb[(size_t)hc * kT + gp]) : (short)0;
}

__global__ __launch_bounds__(256, 3) void dconv_mfma(
    const float* __restrict__ x, const float* __restrict__ W,
    const float* __restrict__ bias, float* __restrict__ out)
{
    __shared__ __align__(16) short xs[130 * kLStride];   // 35.4 KB

    const int tid  = threadIdx.x;
    const int lane = tid & 63;
    const int wv   = tid >> 6;                  // wave -> output rows [32*wv, 32*wv+32)
    const int bb   = blockIdx.x / kNTiles;
    const int tile = blockIdx.x % kNTiles;
    const int p0   = tile * kNP;

    // ---------------- W fragments (A-operand layout) ----------------
    // A[m][k]: m = lane&15 (o), k = (lane>>4)*8 + j (c). Raw W[o][c][tap]:
    // float4 covers 2 c x 2 taps; split taps in-register.
    const int rowbase = wv * 32;
    short8 wf[2][2][4];                         // [tap][rowchunk][kstep]
    #pragma unroll
    for (int cc = 0; cc < 2; ++cc) {
        const int o = rowbase + cc * 16 + (lane & 15);
        #pragma unroll
        for (int s = 0; s < 4; ++s) {
            const int cb = s * 32 + (lane >> 4) * 8;
            const float4* wp = reinterpret_cast<const float4*>(W + o * (kC * 2) + cb * 2);
            float4 wr[4];
            #pragma unroll
            for (int q = 0; q < 4; ++q) wr[q] = wp[q];
            short8 f0, f1;
            #pragma unroll
            for (int q = 0; q < 4; ++q) {
                f0[q * 2 + 0] = f2bf(wr[q].x);  f1[q * 2 + 0] = f2bf(wr[q].y);
                f0[q * 2 + 1] = f2bf(wr[q].z);  f1[q * 2 + 1] = f2bf(wr[q].w);
            }
            wf[0][cc][s] = f0;
            wf[1][cc][s] = f1;
        }
    }

    // ---------------- stage X tile ----------------
    const float* xb = x + (size_t)bb * kC * kT;
    if (p0 + 129 < kT) stage_fast(xb, xs, tid, p0);
    else               stage_guard(xb, xs, tid, p0);

    // ---------------- accumulators initialized with bias ----------------
    // D layout: col = lane&15, row = (lane>>4)*4 + r
    f32x4 acc[2][8];                            // [rowchunk][colchunk]
    #pragma unroll
    for (int cc = 0; cc < 2; ++cc) {
        const int ob = rowbase + cc * 16 + (lane >> 4) * 4;
        f32x4 a;
        a[0] = bias[ob + 0]; a[1] = bias[ob + 1];
        a[2] = bias[ob + 2]; a[3] = bias[ob + 3];
        #pragma unroll
        for (int nc = 0; nc < 8; ++nc) acc[cc][nc] = a;
    }

    __syncthreads();

    // ---------------- MFMA main loop: 2 taps x 4 k-steps x 8 col-chunks x 2 rowchunks --
    #pragma unroll
    for (int tap = 0; tap < 2; ++tap) {
        #pragma unroll
        for (int s = 0; s < 4; ++s) {
            const int cb = s * 32 + (lane >> 4) * 8;
            #pragma unroll
            for (int nc = 0; nc < 8; ++nc) {
                // B[k][n]: n = lane&15 (pos), k = (lane>>4)*8 + j (c)
                const int pos = nc * 16 + (lane & 15) + 2 * tap;
                const short8 bf = *reinterpret_cast<const short8*>(xs + pos * kLStride + cb);
                acc[0][nc] = __builtin_amdgcn_mfma_f32_16x16x32_bf16(wf[tap][0][s], bf, acc[0][nc], 0, 0, 0);
                acc[1][nc] = __builtin_amdgcn_mfma_f32_16x16x32_bf16(wf[tap][1][s], bf, acc[1][nc], 0, 0, 0);
            }
        }
    }

    // ---------------- store ----------------
    float* ob = out + (size_t)bb * kOut * kP;
    #pragma unroll
    for (int nc = 0; nc < 8; ++nc) {
        const int col = p0 + nc * 16 + (lane & 15);
        if (col < kP) {
            #pragma unroll
            for (int cc = 0; cc < 2; ++cc) {
                const int orow = rowbase + cc * 16 + (lane >> 4) * 4;
                #pragma unroll
                for (int r = 0; r < 4; ++r) {
                    ob[(size_t)(orow + r) * kP + col] = acc[cc][nc][r];
                }
            }
        }
    }
}

}  // namespace

extern "C" void kernel_launch(void* const* d_in, const int* in_sizes, int n_in,
                              void* d_out, int out_size, void* d_ws, size_t ws_size,
                              hipStream_t stream) {
    const float* x    = (const float*)d_in[0];
    const float* W    = (const float*)d_in[1];
    const float* bias = (const float*)d_in[2];
    float* out        = (float*)d_out;

    dim3 grid(kB * kNTiles);   // 8 * 257 = 2056 blocks
    dim3 block(256);
    hipLaunchKernelGGL(dconv_mfma, grid, block, 0, stream, x, W, bias, out);
}